// Round 1
// baseline (268.721 us; speedup 1.0000x reference)
//
#include <hip/hip_runtime.h>
#include <hip/hip_bf16.h>
#include <cstddef>

// Problem constants (from reference setup_inputs):
//   x: (B=8, C=64, H=256, W=256) fp32
//   w_sub: (C,LD=8), b_sub: (LD), w_up: (LD,C), b_up: (C), mb: (LD,MEM=128), mu: (1)
constexpr int B = 8, C = 64, H = 256, W = 256, LD = 8, MEM = 128;
constexpr int W4 = W / 4;       // 64 float4 per row
constexpr int NSTRIPE = B * W;  // 2048
constexpr int ROWS = 32;        // rows of a plane per k_scale block

// ---------------------------------------------------------------------------
// Kernel 1: per-(b,c) plane, mean over H for every w.
// ymean[(b*W + w)*C + c] = (1/H) * sum_h x[b,c,h,w]
// Block = 256 threads: lane group hg = t>>6 (4 h-phases), w4 = t&63 (float4 col).
// float4 coalesced loads (16B/lane), LDS combine of the 4 h-phases.
// ---------------------------------------------------------------------------
__global__ __launch_bounds__(256) void k_mean(const float* __restrict__ x,
                                              float* __restrict__ ymean) {
    const int bc = blockIdx.x;          // b*C + c
    const int b  = bc >> 6;
    const int c  = bc & 63;
    const int t  = threadIdx.x;
    const int w4 = t & 63;
    const int hg = t >> 6;              // 0..3

    const float4* plane = reinterpret_cast<const float4*>(x + (size_t)bc * H * W);
    float sx = 0.f, sy = 0.f, sz = 0.f, sw = 0.f;
    #pragma unroll 4
    for (int h = hg; h < H; h += 4) {
        float4 v = plane[h * W4 + w4];
        sx += v.x; sy += v.y; sz += v.z; sw += v.w;
    }

    __shared__ float4 part[256];
    part[t] = make_float4(sx, sy, sz, sw);
    __syncthreads();

    if (hg == 0) {
        float4 a = part[t], p1 = part[t + 64], p2 = part[t + 128], p3 = part[t + 192];
        const float inv = 1.0f / (float)H;
        float r0 = (a.x + p1.x + p2.x + p3.x) * inv;
        float r1 = (a.y + p1.y + p2.y + p3.y) * inv;
        float r2 = (a.z + p1.z + p2.z + p3.z) * inv;
        float r3 = (a.w + p1.w + p2.w + p3.w) * inv;
        const int wbase = w4 * 4;
        size_t o = ((size_t)b * W + wbase) * C + c;
        ymean[o]         = r0;
        ymean[o + C]     = r1;
        ymean[o + 2 * C] = r2;
        ymean[o + 3 * C] = r3;
    }
}

// ---------------------------------------------------------------------------
// Kernel 2: per-stripe gate. One block (128 threads) per stripe s in [0,2048).
//   low = y @ w_sub + b_sub                    (LD=8)
//   f   = softmax(low @ mb * LD^-0.5)          (MEM=128)
//   y1  = f @ mb^T                             (LD=8)
//   gate = sigmoid(y1 @ w_up + b_up) * mu      (C=64)
// ---------------------------------------------------------------------------
__global__ __launch_bounds__(128) void k_gate(const float* __restrict__ ymean,
                                              const float* __restrict__ w_sub,
                                              const float* __restrict__ b_sub,
                                              const float* __restrict__ w_up,
                                              const float* __restrict__ b_up,
                                              const float* __restrict__ mb,
                                              const float* __restrict__ mu,
                                              float* __restrict__ gate) {
    const int s = blockIdx.x;
    const int t = threadIdx.x;

    __shared__ float y[C];
    __shared__ float low[LD];
    __shared__ float f[MEM];
    __shared__ float red[MEM];
    __shared__ float y1[LD];

    if (t < C) y[t] = ymean[(size_t)s * C + t];
    __syncthreads();

    if (t < LD) {
        float acc = b_sub[t];
        for (int c = 0; c < C; ++c) acc += y[c] * w_sub[c * LD + t];
        low[t] = acc;
    }
    __syncthreads();

    // f1[t] for t in [0,128)
    const float scale = 0.35355339059327373f; // 8^-0.5
    float v = 0.f;
    #pragma unroll
    for (int l = 0; l < LD; ++l) v += low[l] * mb[l * MEM + t];
    v *= scale;

    // softmax over 128 (== blockDim.x)
    red[t] = v;
    __syncthreads();
    for (int off = 64; off > 0; off >>= 1) {
        if (t < off) red[t] = fmaxf(red[t], red[t + off]);
        __syncthreads();
    }
    const float m = red[0];
    __syncthreads();
    const float e = expf(v - m);
    red[t] = e;
    __syncthreads();
    for (int off = 64; off > 0; off >>= 1) {
        if (t < off) red[t] += red[t + off];
        __syncthreads();
    }
    const float invsum = 1.0f / red[0];
    f[t] = e * invsum;
    __syncthreads();

    if (t < LD) {
        float acc = 0.f;
        for (int k = 0; k < MEM; ++k) acc += f[k] * mb[t * MEM + k];
        y1[t] = acc;
    }
    __syncthreads();

    if (t < C) {
        float acc = b_up[t];
        #pragma unroll
        for (int l = 0; l < LD; ++l) acc += y1[l] * w_up[l * C + t];
        float g = 1.0f / (1.0f + expf(-acc));
        gate[(size_t)s * C + t] = g * mu[0];
    }
}

// ---------------------------------------------------------------------------
// Kernel 3: out[b,c,h,w] = x[b,c,h,w] * gate[(b*W+w)*C + c]
// grid = (H/ROWS, B*C), block = 256. float4 stream; since the per-thread
// float4-column index (idx & 63) is invariant under i += 256, the 4 gate
// values are hoisted to registers (no per-iteration LDS reads).
// ---------------------------------------------------------------------------
__global__ __launch_bounds__(256) void k_scale(const float* __restrict__ x,
                                               const float* __restrict__ gate,
                                               float* __restrict__ out) {
    const int bc = blockIdx.y;
    const int b  = bc >> 6;
    const int c  = bc & 63;
    const int t  = threadIdx.x;

    __shared__ float g[W];
    if (t < W) g[t] = gate[((size_t)b * W + t) * C + c];
    __syncthreads();

    const int w4 = t & 63;                 // invariant float4 column for this thread
    const float g0 = g[w4 * 4 + 0];
    const float g1 = g[w4 * 4 + 1];
    const float g2 = g[w4 * 4 + 2];
    const float g3 = g[w4 * 4 + 3];

    const float4* xp = reinterpret_cast<const float4*>(x + (size_t)bc * H * W);
    float4* op       = reinterpret_cast<float4*>(out + (size_t)bc * H * W);

    const int base = blockIdx.x * (ROWS * W4);
    #pragma unroll 4
    for (int i = t; i < ROWS * W4; i += 256) {
        const int idx = base + i;
        float4 v = xp[idx];
        v.x *= g0; v.y *= g1; v.z *= g2; v.w *= g3;
        op[idx] = v;
    }
}

extern "C" void kernel_launch(void* const* d_in, const int* in_sizes, int n_in,
                              void* d_out, int out_size, void* d_ws, size_t ws_size,
                              hipStream_t stream) {
    const float* x     = (const float*)d_in[0];
    const float* w_sub = (const float*)d_in[1];
    const float* b_sub = (const float*)d_in[2];
    const float* w_up  = (const float*)d_in[3];
    const float* b_up  = (const float*)d_in[4];
    const float* mb    = (const float*)d_in[5];
    const float* mu    = (const float*)d_in[6];
    float* out = (float*)d_out;

    // Workspace: ymean (2048*64 f32) + gate (2048*64 f32) = 1 MiB total.
    float* ymean = (float*)d_ws;
    float* gate  = ymean + (size_t)NSTRIPE * C;

    k_mean<<<B * C, 256, 0, stream>>>(x, ymean);
    k_gate<<<NSTRIPE, 128, 0, stream>>>(ymean, w_sub, b_sub, w_up, b_up, mb, mu, gate);
    k_scale<<<dim3(H / ROWS, B * C), 256, 0, stream>>>(x, gate, out);
}